// Round 1
// baseline (1219.224 us; speedup 1.0000x reference)
//
#include <hip/hip_runtime.h>

constexpr int B_ = 2;
constexpr int T_ = 2048;
constexpr int C_ = 1024;
constexpr int H_ = 16;
constexpr int D_ = 64;

// ---------------------------------------------------------------------------
// Tiled fp32 GEMM: out = X(M,C) @ W(C,C)  [+ bias]
// MODE 0: scatter output to (B,H,T,D) layout (n-tile of 64 == exactly one head)
// MODE 1: row-major output + bias
// Tiles: BM=BN=64, BK=16; 256 threads, 4x4 accum per thread.
// As stored k-major (transposed) so compute reads are float4 for both A and B.
// ---------------------------------------------------------------------------
template<int MODE>
__global__ __launch_bounds__(256)
void gemm_k(const float* __restrict__ X, const float* __restrict__ W,
            const float* __restrict__ bias, float* __restrict__ out)
{
    __shared__ float As[16][68];   // [k][m]  (transposed; pad 68 -> 2-way stores)
    __shared__ float Bs[16][68];   // [k][n]

    const int tid = threadIdx.x;
    const int tx = tid & 15, ty = tid >> 4;
    const int m0 = blockIdx.y * 64, n0 = blockIdx.x * 64;
    const int ar = tid >> 2,  ac = (tid & 3) * 4;   // A tile: 64 rows x 16 k
    const int br = tid >> 4,  bc = (tid & 15) * 4;  // B tile: 16 k x 64 n

    float acc[4][4] = {};
    const float* Xp = X + (size_t)(m0 + ar) * C_ + ac;
    const float* Wp = W + (size_t)br * C_ + n0 + bc;

    for (int k0 = 0; k0 < C_; k0 += 16) {
        float4 av = *(const float4*)(Xp + k0);
        float4 bv = *(const float4*)(Wp + (size_t)k0 * C_);
        As[ac + 0][ar] = av.x;
        As[ac + 1][ar] = av.y;
        As[ac + 2][ar] = av.z;
        As[ac + 3][ar] = av.w;
        *(float4*)&Bs[br][bc] = bv;
        __syncthreads();
#pragma unroll
        for (int kk = 0; kk < 16; ++kk) {
            float4 a4 = *(const float4*)&As[kk][ty * 4];
            float4 b4 = *(const float4*)&Bs[kk][tx * 4];
            const float a[4] = {a4.x, a4.y, a4.z, a4.w};
            const float b[4] = {b4.x, b4.y, b4.z, b4.w};
#pragma unroll
            for (int i = 0; i < 4; ++i)
#pragma unroll
                for (int j = 0; j < 4; ++j)
                    acc[i][j] = fmaf(a[i], b[j], acc[i][j]);
        }
        __syncthreads();
    }

    if (MODE == 0) {
        const int h = n0 >> 6;                 // n-tile == head
#pragma unroll
        for (int i = 0; i < 4; ++i) {
            const int m = m0 + ty * 4 + i;     // tile never crosses batch
            const int b = m >> 11;             // m / 2048
            const int t = m & (T_ - 1);
            float4 v = make_float4(acc[i][0], acc[i][1], acc[i][2], acc[i][3]);
            *(float4*)(out + ((size_t)(b * H_ + h) * T_ + t) * D_ + tx * 4) = v;
        }
    } else {
        const float4 bb = *(const float4*)(bias + n0 + tx * 4);
#pragma unroll
        for (int i = 0; i < 4; ++i) {
            const int m = m0 + ty * 4 + i;
            float4 v = make_float4(acc[i][0] + bb.x, acc[i][1] + bb.y,
                                   acc[i][2] + bb.z, acc[i][3] + bb.w);
            *(float4*)(out + (size_t)m * C_ + n0 + tx * 4) = v;
        }
    }
}

// ---------------------------------------------------------------------------
// Flash-style causal attention, fp32.
// Block = (b*H+h, 64-row Q tile), 256 threads, 4x4 per thread.
// Qs/Ks stored d-major so S = Q^T K is an outer-product loop over d (b128+FMA).
// P^T aliases the K buffer (not needed simultaneously) -> 50 KB LDS.
// ---------------------------------------------------------------------------
__global__ __launch_bounds__(256)
void attn_k(const float* __restrict__ q, const float* __restrict__ k,
            const float* __restrict__ v, float* __restrict__ att)
{
    __shared__ float Qs[64][64];   // [d][r]  (read: 4 broadcast addrs, free)
    __shared__ float KP[64 * 68];  // Ks as [d][c] stride 68; later P^T as [c][r]
    __shared__ float Vs[64][64];   // [c][d]

    const int tid = threadIdx.x;
    const int tx = tid & 15, ty = tid >> 4;
    const int qt = blockIdx.x;
    const int bh = blockIdx.y;
    const int b  = bh >> 4, h = bh & 15;
    const int q0 = qt * 64;

    // --- stage Q tile, transposed to [d][r] (once per block) ---
    {
        const float* qp = q + ((size_t)bh * T_ + q0) * D_;
#pragma unroll
        for (int c4 = 0; c4 < 4; ++c4) {
            const int idx = tid + c4 * 256;
            const int row = idx >> 4, d4 = (idx & 15) * 4;
            float4 qv = *(const float4*)(qp + row * D_ + d4);
            Qs[d4 + 0][row] = qv.x;
            Qs[d4 + 1][row] = qv.y;
            Qs[d4 + 2][row] = qv.z;
            Qs[d4 + 3][row] = qv.w;
        }
    }

    float m_i[4], l_i[4], acc_o[4][4] = {};
#pragma unroll
    for (int i = 0; i < 4; ++i) { m_i[i] = -1e30f; l_i[i] = 0.0f; }

    for (int jt = 0; jt <= qt; ++jt) {
        __syncthreads();   // prev PV reads of KP/Vs complete before restage
        // --- stage K (d-major into KP) and V (row-major) ---
        {
            const float* kp = k + ((size_t)bh * T_ + jt * 64) * D_;
            const float* vp = v + ((size_t)bh * T_ + jt * 64) * D_;
#pragma unroll
            for (int c4 = 0; c4 < 4; ++c4) {
                const int idx = tid + c4 * 256;
                const int row = idx >> 4, d4 = (idx & 15) * 4;
                float4 kv = *(const float4*)(kp + row * D_ + d4);
                KP[(d4 + 0) * 68 + row] = kv.x;
                KP[(d4 + 1) * 68 + row] = kv.y;
                KP[(d4 + 2) * 68 + row] = kv.z;
                KP[(d4 + 3) * 68 + row] = kv.w;
                *(float4*)&Vs[row][d4] = *(const float4*)(vp + row * D_ + d4);
            }
        }
        __syncthreads();

        // --- S = Q^T K (outer product over d) ---
        float s[4][4] = {};
#pragma unroll 8
        for (int d = 0; d < 64; ++d) {
            float4 a4 = *(const float4*)&Qs[d][ty * 4];
            float4 b4 = *(const float4*)&KP[d * 68 + tx * 4];
            const float a[4] = {a4.x, a4.y, a4.z, a4.w};
            const float bq[4] = {b4.x, b4.y, b4.z, b4.w};
#pragma unroll
            for (int i = 0; i < 4; ++i)
#pragma unroll
            for (int j = 0; j < 4; ++j)
                s[i][j] = fmaf(a[i], bq[j], s[i][j]);
        }
        __syncthreads();   // all Ks reads done before P^T overwrites KP

        // --- scale + causal mask (only diagonal tile needs mask) ---
        const float sc = 0.125f;  // 1/sqrt(64)
        if (jt == qt) {
#pragma unroll
            for (int i = 0; i < 4; ++i)
#pragma unroll
            for (int j = 0; j < 4; ++j) {
                const int r = ty * 4 + i, c = tx * 4 + j;
                s[i][j] = (c <= r) ? s[i][j] * sc : -1e30f;
            }
        } else {
#pragma unroll
            for (int i = 0; i < 4; ++i)
#pragma unroll
            for (int j = 0; j < 4; ++j) s[i][j] *= sc;
        }

        // --- online softmax (rows live in a 16-lane tx group) ---
        float p[4][4];
#pragma unroll
        for (int i = 0; i < 4; ++i) {
            float mx = fmaxf(fmaxf(s[i][0], s[i][1]), fmaxf(s[i][2], s[i][3]));
#pragma unroll
            for (int off = 1; off < 16; off <<= 1)
                mx = fmaxf(mx, __shfl_xor(mx, off, 16));
            const float mnew = fmaxf(m_i[i], mx);
            const float alpha = __expf(m_i[i] - mnew);
            m_i[i] = mnew;
            float rs = 0.0f;
#pragma unroll
            for (int j = 0; j < 4; ++j) {
                p[i][j] = __expf(s[i][j] - mnew);
                rs += p[i][j];
            }
#pragma unroll
            for (int off = 1; off < 16; off <<= 1)
                rs += __shfl_xor(rs, off, 16);
            l_i[i] = l_i[i] * alpha + rs;
#pragma unroll
            for (int j = 0; j < 4; ++j) acc_o[i][j] *= alpha;
        }

        // --- write P^T into KP: [c][r] stride 68 ---
#pragma unroll
        for (int i = 0; i < 4; ++i)
#pragma unroll
        for (int j = 0; j < 4; ++j)
            KP[(tx * 4 + j) * 68 + (ty * 4 + i)] = p[i][j];
        __syncthreads();

        // --- O += P V (outer product over c) ---
#pragma unroll 8
        for (int c = 0; c < 64; ++c) {
            float4 p4 = *(const float4*)&KP[c * 68 + ty * 4];
            float4 v4 = *(const float4*)&Vs[c][tx * 4];
            const float pa[4] = {p4.x, p4.y, p4.z, p4.w};
            const float vb[4] = {v4.x, v4.y, v4.z, v4.w};
#pragma unroll
            for (int i = 0; i < 4; ++i)
#pragma unroll
            for (int j = 0; j < 4; ++j)
                acc_o[i][j] = fmaf(pa[i], vb[j], acc_o[i][j]);
        }
    }

    // --- epilogue: O /= l, write to (B,T,C) intermediate ---
#pragma unroll
    for (int i = 0; i < 4; ++i) {
        const float inv = 1.0f / l_i[i];
        const int t = q0 + ty * 4 + i;
        float4 o = make_float4(acc_o[i][0] * inv, acc_o[i][1] * inv,
                               acc_o[i][2] * inv, acc_o[i][3] * inv);
        *(float4*)(att + ((size_t)b * T_ + t) * C_ + h * 64 + tx * 4) = o;
    }
}

// ---------------------------------------------------------------------------
extern "C" void kernel_launch(void* const* d_in, const int* in_sizes, int n_in,
                              void* d_out, int out_size, void* d_ws, size_t ws_size,
                              hipStream_t stream)
{
    (void)in_sizes; (void)n_in; (void)out_size; (void)ws_size;
    const float* x  = (const float*)d_in[0];
    const float* Wq = (const float*)d_in[1];
    const float* Wk = (const float*)d_in[2];
    const float* Wv = (const float*)d_in[3];
    const float* Wo = (const float*)d_in[4];
    const float* bo = (const float*)d_in[5];

    float* out  = (float*)d_out;                       // (B,T,C)
    float* kout = out  + (size_t)B_ * T_ * C_;         // (B,H,T,D)
    float* vout = kout + (size_t)B_ * H_ * T_ * D_;    // (B,H,T,D)

    float* qws   = (float*)d_ws;                       // (B,H,T,D) 16 MB
    float* attws = qws + (size_t)B_ * H_ * T_ * D_;    // (B,T,C)   16 MB

    dim3 gg(C_ / 64, (B_ * T_) / 64);   // (16, 64)
    gemm_k<0><<<gg, 256, 0, stream>>>(x, Wq, nullptr, qws);
    gemm_k<0><<<gg, 256, 0, stream>>>(x, Wk, nullptr, kout);
    gemm_k<0><<<gg, 256, 0, stream>>>(x, Wv, nullptr, vout);

    attn_k<<<dim3(T_ / 64, B_ * H_), 256, 0, stream>>>(qws, kout, vout, attws);

    gemm_k<1><<<gg, 256, 0, stream>>>(attws, Wo, bo, out);
}

// Round 2
// 570.128 us; speedup vs baseline: 2.1385x; 2.1385x over previous
//
#include <hip/hip_runtime.h>

constexpr int B_ = 2;
constexpr int T_ = 2048;
constexpr int C_ = 1024;
constexpr int H_ = 16;
constexpr int D_ = 64;
constexpr int M_ = B_ * T_;   // 4096 rows

typedef __attribute__((ext_vector_type(8))) short bf16x8;   // 8 bf16 = 4 VGPRs
typedef __attribute__((ext_vector_type(4))) float f32x4;
typedef const __attribute__((address_space(1))) void gaddr_t;
typedef __attribute__((address_space(3))) void laddr_t;

__device__ __forceinline__ unsigned short f2bf(float f) {   // fp32 -> bf16 RNE
    unsigned u = __float_as_uint(f);
    return (unsigned short)((u + 0x7fffu + ((u >> 16) & 1u)) >> 16);
}
__device__ __forceinline__ float bf2f(unsigned short h) {
    return __uint_as_float((unsigned)h << 16);
}

// ---------------------------------------------------------------------------
// x (fp32) -> xb (bf16), flat
// ---------------------------------------------------------------------------
__global__ __launch_bounds__(256)
void cast_x(const float* __restrict__ x, unsigned short* __restrict__ xb, int n4)
{
    for (int i = blockIdx.x * 256 + threadIdx.x; i < n4; i += gridDim.x * 256) {
        float4 v = ((const float4*)x)[i];
        ushort4 o;
        o.x = f2bf(v.x); o.y = f2bf(v.y); o.z = f2bf(v.z); o.w = f2bf(v.w);
        ((ushort4*)xb)[i] = o;
    }
}

// ---------------------------------------------------------------------------
// W (K x N fp32, row-major) -> Wt (N x K bf16, row-major) for 4 weights.
// blockIdx.z selects the weight. 64x64 tiles via LDS.
// ---------------------------------------------------------------------------
__global__ __launch_bounds__(256)
void tcast_w(const float* __restrict__ Wq, const float* __restrict__ Wk,
             const float* __restrict__ Wv, const float* __restrict__ Wo,
             unsigned short* __restrict__ wtb)
{
    __shared__ float tile[64][65];
    const int z = blockIdx.z;
    const float* W = (z == 0) ? Wq : (z == 1) ? Wk : (z == 2) ? Wv : Wo;
    unsigned short* O = wtb + (size_t)z * C_ * C_;

    const int tid = threadIdx.x;
    const int n0 = blockIdx.x * 64, k0 = blockIdx.y * 64;
    const int r = tid >> 4, c4 = (tid & 15) * 4;

#pragma unroll
    for (int i = 0; i < 4; ++i) {
        const int kk = i * 16 + r;
        float4 v = *(const float4*)(W + (size_t)(k0 + kk) * C_ + n0 + c4);
        tile[c4 + 0][kk] = v.x;
        tile[c4 + 1][kk] = v.y;
        tile[c4 + 2][kk] = v.z;
        tile[c4 + 3][kk] = v.w;
    }
    __syncthreads();
#pragma unroll
    for (int i = 0; i < 4; ++i) {
        const int nn = i * 16 + r;
        ushort4 o;
        o.x = f2bf(tile[nn][c4 + 0]);
        o.y = f2bf(tile[nn][c4 + 1]);
        o.z = f2bf(tile[nn][c4 + 2]);
        o.w = f2bf(tile[nn][c4 + 3]);
        *(ushort4*)(O + (size_t)(n0 + nn) * C_ + k0 + c4) = o;
    }
}

// ---------------------------------------------------------------------------
// Fused QKV bf16 MFMA GEMM. A = xb (M x K), Bt = wtb[which] (N x K).
// Tile 128x128, BK=32, 256 thr = 4 waves (2x2 quadrants of 64x64),
// wave = 4x4 grid of 16x16x32 MFMAs. global_load_lds 16B staging.
// Output: q -> qb (bf16, B,H,T,D), k/v -> kout/vout (fp32, B,H,T,D).
// ---------------------------------------------------------------------------
__global__ __launch_bounds__(256)
void gemm_qkv(const unsigned short* __restrict__ xb, const unsigned short* __restrict__ wtb,
              unsigned short* __restrict__ qb, float* __restrict__ kout,
              float* __restrict__ vout)
{
    __shared__ unsigned short As[128 * 32];
    __shared__ unsigned short Bs[128 * 32];

    const int tid = threadIdx.x;
    const int which = blockIdx.x >> 3;             // 0=q 1=k 2=v
    const int n0 = (blockIdx.x & 7) * 128;
    const int m0 = blockIdx.y * 128;
    const unsigned short* wt = wtb + (size_t)which * C_ * C_;

    const int lane = tid & 63, w = tid >> 6;
    const int wm = (w >> 1) * 64, wn = (w & 1) * 64;
    const int fr = lane & 15, qd = lane >> 4;

    // staging chunks: c = tid, tid+256; row=c>>2, k8=(c&3)*8; lds byte off = c*16
    const int c0 = tid, c1 = tid + 256;
    const int ar0 = c0 >> 2, ak0 = (c0 & 3) * 8;
    const int ar1 = c1 >> 2, ak1 = (c1 & 3) * 8;

    f32x4 acc[4][4] = {};

    for (int k0 = 0; k0 < C_; k0 += 32) {
        __builtin_amdgcn_global_load_lds((gaddr_t*)(xb + (size_t)(m0 + ar0) * C_ + k0 + ak0),
                                         (laddr_t*)((char*)As + c0 * 16), 16, 0, 0);
        __builtin_amdgcn_global_load_lds((gaddr_t*)(xb + (size_t)(m0 + ar1) * C_ + k0 + ak1),
                                         (laddr_t*)((char*)As + c1 * 16), 16, 0, 0);
        __builtin_amdgcn_global_load_lds((gaddr_t*)(wt + (size_t)(n0 + ar0) * C_ + k0 + ak0),
                                         (laddr_t*)((char*)Bs + c0 * 16), 16, 0, 0);
        __builtin_amdgcn_global_load_lds((gaddr_t*)(wt + (size_t)(n0 + ar1) * C_ + k0 + ak1),
                                         (laddr_t*)((char*)Bs + c1 * 16), 16, 0, 0);
        __syncthreads();

        bf16x8 af[4], bfv[4];
#pragma unroll
        for (int mt = 0; mt < 4; ++mt)
            af[mt] = *(const bf16x8*)&As[(wm + mt * 16 + fr) * 32 + qd * 8];
#pragma unroll
        for (int nt = 0; nt < 4; ++nt)
            bfv[nt] = *(const bf16x8*)&Bs[(wn + nt * 16 + fr) * 32 + qd * 8];
#pragma unroll
        for (int mt = 0; mt < 4; ++mt)
#pragma unroll
            for (int nt = 0; nt < 4; ++nt)
                acc[mt][nt] = __builtin_amdgcn_mfma_f32_16x16x32_bf16(
                    af[mt], bfv[nt], acc[mt][nt], 0, 0, 0);
        __syncthreads();
    }

    // C/D layout: col = lane&15, row = (lane>>4)*4 + reg  [m89-verified]
#pragma unroll
    for (int mt = 0; mt < 4; ++mt) {
#pragma unroll
        for (int nt = 0; nt < 4; ++nt) {
            const int ncol = n0 + wn + nt * 16 + fr;
            const int h = ncol >> 6, d = ncol & 63;
#pragma unroll
            for (int r = 0; r < 4; ++r) {
                const int mm = m0 + wm + mt * 16 + qd * 4 + r;
                const int b = mm >> 11, t = mm & (T_ - 1);
                const size_t off = ((size_t)(b * H_ + h) * T_ + t) * D_ + d;
                const float val = acc[mt][nt][r];
                if (which == 0)      qb[off]   = f2bf(val);
                else if (which == 1) kout[off] = val;
                else                 vout[off] = val;
            }
        }
    }
}

// ---------------------------------------------------------------------------
// Output projection: out = attb @ Wo + bo (bf16 MFMA, fp32 out, row-major)
// ---------------------------------------------------------------------------
__global__ __launch_bounds__(256)
void gemm_o(const unsigned short* __restrict__ ab, const unsigned short* __restrict__ wot,
            const float* __restrict__ bo, float* __restrict__ out)
{
    __shared__ unsigned short As[128 * 32];
    __shared__ unsigned short Bs[128 * 32];

    const int tid = threadIdx.x;
    const int n0 = blockIdx.x * 128;
    const int m0 = blockIdx.y * 128;

    const int lane = tid & 63, w = tid >> 6;
    const int wm = (w >> 1) * 64, wn = (w & 1) * 64;
    const int fr = lane & 15, qd = lane >> 4;

    const int c0 = tid, c1 = tid + 256;
    const int ar0 = c0 >> 2, ak0 = (c0 & 3) * 8;
    const int ar1 = c1 >> 2, ak1 = (c1 & 3) * 8;

    f32x4 acc[4][4] = {};

    for (int k0 = 0; k0 < C_; k0 += 32) {
        __builtin_amdgcn_global_load_lds((gaddr_t*)(ab + (size_t)(m0 + ar0) * C_ + k0 + ak0),
                                         (laddr_t*)((char*)As + c0 * 16), 16, 0, 0);
        __builtin_amdgcn_global_load_lds((gaddr_t*)(ab + (size_t)(m0 + ar1) * C_ + k0 + ak1),
                                         (laddr_t*)((char*)As + c1 * 16), 16, 0, 0);
        __builtin_amdgcn_global_load_lds((gaddr_t*)(wot + (size_t)(n0 + ar0) * C_ + k0 + ak0),
                                         (laddr_t*)((char*)Bs + c0 * 16), 16, 0, 0);
        __builtin_amdgcn_global_load_lds((gaddr_t*)(wot + (size_t)(n0 + ar1) * C_ + k0 + ak1),
                                         (laddr_t*)((char*)Bs + c1 * 16), 16, 0, 0);
        __syncthreads();

        bf16x8 af[4], bfv[4];
#pragma unroll
        for (int mt = 0; mt < 4; ++mt)
            af[mt] = *(const bf16x8*)&As[(wm + mt * 16 + fr) * 32 + qd * 8];
#pragma unroll
        for (int nt = 0; nt < 4; ++nt)
            bfv[nt] = *(const bf16x8*)&Bs[(wn + nt * 16 + fr) * 32 + qd * 8];
#pragma unroll
        for (int mt = 0; mt < 4; ++mt)
#pragma unroll
            for (int nt = 0; nt < 4; ++nt)
                acc[mt][nt] = __builtin_amdgcn_mfma_f32_16x16x32_bf16(
                    af[mt], bfv[nt], acc[mt][nt], 0, 0, 0);
        __syncthreads();
    }

#pragma unroll
    for (int mt = 0; mt < 4; ++mt) {
#pragma unroll
        for (int nt = 0; nt < 4; ++nt) {
            const int ncol = n0 + wn + nt * 16 + fr;
            const float bb = bo[ncol];
#pragma unroll
            for (int r = 0; r < 4; ++r) {
                const int mm = m0 + wm + mt * 16 + qd * 4 + r;
                out[(size_t)mm * C_ + ncol] = acc[mt][nt][r] + bb;
            }
        }
    }
}

// ---------------------------------------------------------------------------
// Flash-style causal attention, fp32 compute. Q in bf16, K/V fp32.
// Block handles TWO Q-tiles (qt, 31-qt) -> 512 blocks, each 33 KV-iters
// (perfect load balance). Output written as bf16 (feeds gemm_o).
// ---------------------------------------------------------------------------
__global__ __launch_bounds__(256)
void attn_k(const unsigned short* __restrict__ qb, const float* __restrict__ k,
            const float* __restrict__ v, unsigned short* __restrict__ attb)
{
    __shared__ float Qs[64][64];   // [d][r]
    __shared__ float KP[64 * 68];  // Ks as [d][c] stride 68; later P^T as [c][r]
    __shared__ float Vs[64][64];   // [c][d]

    const int tid = threadIdx.x;
    const int tx = tid & 15, ty = tid >> 4;
    const int bh = blockIdx.y;
    const int b  = bh >> 4, h = bh & 15;

    for (int rep = 0; rep < 2; ++rep) {
        const int qt = rep ? (31 - (int)blockIdx.x) : (int)blockIdx.x;
        const int q0 = qt * 64;

        // --- stage Q tile (bf16 -> fp32), transposed to [d][r] ---
        {
            const unsigned short* qp = qb + ((size_t)bh * T_ + q0) * D_;
#pragma unroll
            for (int c4 = 0; c4 < 4; ++c4) {
                const int idx = tid + c4 * 256;
                const int row = idx >> 4, d4 = (idx & 15) * 4;
                ushort4 qv = *(const ushort4*)(qp + row * D_ + d4);
                Qs[d4 + 0][row] = bf2f(qv.x);
                Qs[d4 + 1][row] = bf2f(qv.y);
                Qs[d4 + 2][row] = bf2f(qv.z);
                Qs[d4 + 3][row] = bf2f(qv.w);
            }
        }

        float m_i[4], l_i[4], acc_o[4][4] = {};
#pragma unroll
        for (int i = 0; i < 4; ++i) { m_i[i] = -1e30f; l_i[i] = 0.0f; }

        for (int jt = 0; jt <= qt; ++jt) {
            __syncthreads();   // prev PV reads of KP/Vs complete before restage
            {
                const float* kp = k + ((size_t)bh * T_ + jt * 64) * D_;
                const float* vp = v + ((size_t)bh * T_ + jt * 64) * D_;
#pragma unroll
                for (int c4 = 0; c4 < 4; ++c4) {
                    const int idx = tid + c4 * 256;
                    const int row = idx >> 4, d4 = (idx & 15) * 4;
                    float4 kv = *(const float4*)(kp + row * D_ + d4);
                    KP[(d4 + 0) * 68 + row] = kv.x;
                    KP[(d4 + 1) * 68 + row] = kv.y;
                    KP[(d4 + 2) * 68 + row] = kv.z;
                    KP[(d4 + 3) * 68 + row] = kv.w;
                    *(float4*)&Vs[row][d4] = *(const float4*)(vp + row * D_ + d4);
                }
            }
            __syncthreads();

            // --- S = Q^T K (outer product over d) ---
            float s[4][4] = {};
#pragma unroll 8
            for (int d = 0; d < 64; ++d) {
                float4 a4 = *(const float4*)&Qs[d][ty * 4];
                float4 b4 = *(const float4*)&KP[d * 68 + tx * 4];
                const float a[4] = {a4.x, a4.y, a4.z, a4.w};
                const float bq[4] = {b4.x, b4.y, b4.z, b4.w};
#pragma unroll
                for (int i = 0; i < 4; ++i)
#pragma unroll
                for (int j = 0; j < 4; ++j)
                    s[i][j] = fmaf(a[i], bq[j], s[i][j]);
            }
            __syncthreads();   // Ks reads done before P^T overwrites KP

            const float sc = 0.125f;  // 1/sqrt(64)
            if (jt == qt) {
#pragma unroll
                for (int i = 0; i < 4; ++i)
#pragma unroll
                for (int j = 0; j < 4; ++j) {
                    const int r = ty * 4 + i, c = tx * 4 + j;
                    s[i][j] = (c <= r) ? s[i][j] * sc : -1e30f;
                }
            } else {
#pragma unroll
                for (int i = 0; i < 4; ++i)
#pragma unroll
                for (int j = 0; j < 4; ++j) s[i][j] *= sc;
            }

            // --- online softmax (rows live in a 16-lane tx group) ---
            float p[4][4];
#pragma unroll
            for (int i = 0; i < 4; ++i) {
                float mx = fmaxf(fmaxf(s[i][0], s[i][1]), fmaxf(s[i][2], s[i][3]));
#pragma unroll
                for (int off = 1; off < 16; off <<= 1)
                    mx = fmaxf(mx, __shfl_xor(mx, off, 16));
                const float mnew = fmaxf(m_i[i], mx);
                const float alpha = __expf(m_i[i] - mnew);
                m_i[i] = mnew;
                float rs = 0.0f;
#pragma unroll
                for (int j = 0; j < 4; ++j) {
                    p[i][j] = __expf(s[i][j] - mnew);
                    rs += p[i][j];
                }
#pragma unroll
                for (int off = 1; off < 16; off <<= 1)
                    rs += __shfl_xor(rs, off, 16);
                l_i[i] = l_i[i] * alpha + rs;
#pragma unroll
                for (int j = 0; j < 4; ++j) acc_o[i][j] *= alpha;
            }

            // --- write P^T into KP: [c][r] stride 68 ---
#pragma unroll
            for (int i = 0; i < 4; ++i)
#pragma unroll
            for (int j = 0; j < 4; ++j)
                KP[(tx * 4 + j) * 68 + (ty * 4 + i)] = p[i][j];
            __syncthreads();

            // --- O += P V (outer product over c) ---
#pragma unroll 8
            for (int c = 0; c < 64; ++c) {
                float4 p4 = *(const float4*)&KP[c * 68 + ty * 4];
                float4 v4 = *(const float4*)&Vs[c][tx * 4];
                const float pa[4] = {p4.x, p4.y, p4.z, p4.w};
                const float vb[4] = {v4.x, v4.y, v4.z, v4.w};
#pragma unroll
                for (int i = 0; i < 4; ++i)
#pragma unroll
                for (int j = 0; j < 4; ++j)
                    acc_o[i][j] = fmaf(pa[i], vb[j], acc_o[i][j]);
            }
        }

        // --- epilogue: O /= l, write bf16 to (B,T,C) ---
#pragma unroll
        for (int i = 0; i < 4; ++i) {
            const float inv = 1.0f / l_i[i];
            const int t = q0 + ty * 4 + i;
            ushort4 o4;
            o4.x = f2bf(acc_o[i][0] * inv);
            o4.y = f2bf(acc_o[i][1] * inv);
            o4.z = f2bf(acc_o[i][2] * inv);
            o4.w = f2bf(acc_o[i][3] * inv);
            *(ushort4*)(attb + ((size_t)b * T_ + t) * C_ + h * 64 + tx * 4) = o4;
        }
        // next rep's Qs writes are safe: all Qs reads ended before the
        // post-S barrier of the last jt iteration.
    }
}

// ---------------------------------------------------------------------------
extern "C" void kernel_launch(void* const* d_in, const int* in_sizes, int n_in,
                              void* d_out, int out_size, void* d_ws, size_t ws_size,
                              hipStream_t stream)
{
    (void)in_sizes; (void)n_in; (void)out_size; (void)ws_size;
    const float* x  = (const float*)d_in[0];
    const float* Wq = (const float*)d_in[1];
    const float* Wk = (const float*)d_in[2];
    const float* Wv = (const float*)d_in[3];
    const float* Wo = (const float*)d_in[4];
    const float* bo = (const float*)d_in[5];

    float* out  = (float*)d_out;                       // (B,T,C)
    float* kout = out  + (size_t)M_ * C_;              // (B,H,T,D) fp32
    float* vout = kout + (size_t)B_ * H_ * T_ * D_;    // (B,H,T,D) fp32

    // workspace: xb(4M) | wtb(4x1M) | qb(4M) | attb(4M) bf16 elems = 32 MB
    unsigned short* xb   = (unsigned short*)d_ws;
    unsigned short* wtb  = xb  + (size_t)M_ * C_;
    unsigned short* qb   = wtb + (size_t)4 * C_ * C_;
    unsigned short* attb = qb  + (size_t)B_ * H_ * T_ * D_;

    cast_x<<<1024, 256, 0, stream>>>(x, xb, (M_ * C_) / 4);
    tcast_w<<<dim3(16, 16, 4), 256, 0, stream>>>(Wq, Wk, Wv, Wo, wtb);

    gemm_qkv<<<dim3(24, M_ / 128), 256, 0, stream>>>(xb, wtb, qb, kout, vout);

    attn_k<<<dim3(16, B_ * H_), 256, 0, stream>>>(qb, kout, vout, attb);

    gemm_o<<<dim3(8, M_ / 128), 256, 0, stream>>>(attb, wtb + (size_t)3 * C_ * C_, bo, out);
}

// Round 3
// 359.315 us; speedup vs baseline: 3.3932x; 1.5867x over previous
//
#include <hip/hip_runtime.h>
#include <hip/hip_bf16.h>

constexpr int B_ = 2;
constexpr int T_ = 2048;
constexpr int C_ = 1024;
constexpr int H_ = 16;
constexpr int D_ = 64;
constexpr int M_ = B_ * T_;   // 4096 rows

typedef __attribute__((ext_vector_type(8))) short bf16x8;   // 8 bf16 = 4 VGPRs
typedef __attribute__((ext_vector_type(4))) float f32x4;
typedef const __attribute__((address_space(1))) void gaddr_t;
typedef __attribute__((address_space(3))) void laddr_t;

__device__ __forceinline__ unsigned short f2bf(float f) {   // fp32 -> bf16 RNE
    unsigned u = __float_as_uint(f);
    return (unsigned short)((u + 0x7fffu + ((u >> 16) & 1u)) >> 16);
}

union BF8 { bf16x8 v; __hip_bfloat162 h[4]; };

__device__ __forceinline__ bf16x8 cvt8(const float4 a, const float4 b) {
    BF8 r;
    r.h[0] = __float22bfloat162_rn(make_float2(a.x, a.y));
    r.h[1] = __float22bfloat162_rn(make_float2(a.z, a.w));
    r.h[2] = __float22bfloat162_rn(make_float2(b.x, b.y));
    r.h[3] = __float22bfloat162_rn(make_float2(b.z, b.w));
    return r.v;
}

// ---------------------------------------------------------------------------
// x (fp32) -> xb (bf16), flat
// ---------------------------------------------------------------------------
__global__ __launch_bounds__(256)
void cast_x(const float* __restrict__ x, unsigned short* __restrict__ xb, int n4)
{
    for (int i = blockIdx.x * 256 + threadIdx.x; i < n4; i += gridDim.x * 256) {
        float4 v = ((const float4*)x)[i];
        union { __hip_bfloat162 h[2]; ushort4 u; } o;
        o.h[0] = __float22bfloat162_rn(make_float2(v.x, v.y));
        o.h[1] = __float22bfloat162_rn(make_float2(v.z, v.w));
        ((ushort4*)xb)[i] = o.u;
    }
}

// ---------------------------------------------------------------------------
// W (K x N fp32, row-major) -> Wt (N x K bf16, row-major) for 4 weights.
// ---------------------------------------------------------------------------
__global__ __launch_bounds__(256)
void tcast_w(const float* __restrict__ Wq, const float* __restrict__ Wk,
             const float* __restrict__ Wv, const float* __restrict__ Wo,
             unsigned short* __restrict__ wtb)
{
    __shared__ float tile[64][65];
    const int z = blockIdx.z;
    const float* W = (z == 0) ? Wq : (z == 1) ? Wk : (z == 2) ? Wv : Wo;
    unsigned short* O = wtb + (size_t)z * C_ * C_;

    const int tid = threadIdx.x;
    const int n0 = blockIdx.x * 64, k0 = blockIdx.y * 64;
    const int r = tid >> 4, c4 = (tid & 15) * 4;

#pragma unroll
    for (int i = 0; i < 4; ++i) {
        const int kk = i * 16 + r;
        float4 v = *(const float4*)(W + (size_t)(k0 + kk) * C_ + n0 + c4);
        tile[c4 + 0][kk] = v.x;
        tile[c4 + 1][kk] = v.y;
        tile[c4 + 2][kk] = v.z;
        tile[c4 + 3][kk] = v.w;
    }
    __syncthreads();
#pragma unroll
    for (int i = 0; i < 4; ++i) {
        const int nn = i * 16 + r;
        ushort4 o;
        o.x = f2bf(tile[nn][c4 + 0]);
        o.y = f2bf(tile[nn][c4 + 1]);
        o.z = f2bf(tile[nn][c4 + 2]);
        o.w = f2bf(tile[nn][c4 + 3]);
        *(ushort4*)(O + (size_t)(n0 + nn) * C_ + k0 + c4) = o;
    }
}

// ---------------------------------------------------------------------------
// Fused QKV bf16 MFMA GEMM (128x128 tile, BK=32, global_load_lds 16B).
// q -> qb (bf16, B,H,T,D); k -> kout (fp32, B,H,T,D);
// v -> vout (fp32, B,H,T,D) + vbt (bf16, B,H,D,T  -- transposed for PV B-frags)
// ---------------------------------------------------------------------------
__global__ __launch_bounds__(256)
void gemm_qkv(const unsigned short* __restrict__ xb, const unsigned short* __restrict__ wtb,
              unsigned short* __restrict__ qb, float* __restrict__ kout,
              float* __restrict__ vout, unsigned short* __restrict__ vbt)
{
    __shared__ unsigned short As[128 * 32];
    __shared__ unsigned short Bs[128 * 32];

    const int tid = threadIdx.x;
    const int which = blockIdx.x >> 3;             // 0=q 1=k 2=v
    const int n0 = (blockIdx.x & 7) * 128;
    const int m0 = blockIdx.y * 128;
    const unsigned short* wt = wtb + (size_t)which * C_ * C_;

    const int lane = tid & 63, w = tid >> 6;
    const int wm = (w >> 1) * 64, wn = (w & 1) * 64;
    const int fr = lane & 15, qd = lane >> 4;

    const int c0 = tid, c1 = tid + 256;
    const int ar0 = c0 >> 2, ak0 = (c0 & 3) * 8;
    const int ar1 = c1 >> 2, ak1 = (c1 & 3) * 8;

    f32x4 acc[4][4] = {};

    for (int k0 = 0; k0 < C_; k0 += 32) {
        __builtin_amdgcn_global_load_lds((gaddr_t*)(xb + (size_t)(m0 + ar0) * C_ + k0 + ak0),
                                         (laddr_t*)((char*)As + c0 * 16), 16, 0, 0);
        __builtin_amdgcn_global_load_lds((gaddr_t*)(xb + (size_t)(m0 + ar1) * C_ + k0 + ak1),
                                         (laddr_t*)((char*)As + c1 * 16), 16, 0, 0);
        __builtin_amdgcn_global_load_lds((gaddr_t*)(wt + (size_t)(n0 + ar0) * C_ + k0 + ak0),
                                         (laddr_t*)((char*)Bs + c0 * 16), 16, 0, 0);
        __builtin_amdgcn_global_load_lds((gaddr_t*)(wt + (size_t)(n0 + ar1) * C_ + k0 + ak1),
                                         (laddr_t*)((char*)Bs + c1 * 16), 16, 0, 0);
        __syncthreads();

        bf16x8 af[4], bfv[4];
#pragma unroll
        for (int mt = 0; mt < 4; ++mt)
            af[mt] = *(const bf16x8*)&As[(wm + mt * 16 + fr) * 32 + qd * 8];
#pragma unroll
        for (int nt = 0; nt < 4; ++nt)
            bfv[nt] = *(const bf16x8*)&Bs[(wn + nt * 16 + fr) * 32 + qd * 8];
#pragma unroll
        for (int mt = 0; mt < 4; ++mt)
#pragma unroll
            for (int nt = 0; nt < 4; ++nt)
                acc[mt][nt] = __builtin_amdgcn_mfma_f32_16x16x32_bf16(
                    af[mt], bfv[nt], acc[mt][nt], 0, 0, 0);
        __syncthreads();
    }

    // C/D layout: col = lane&15, row = (lane>>4)*4 + reg
#pragma unroll
    for (int mt = 0; mt < 4; ++mt) {
#pragma unroll
        for (int nt = 0; nt < 4; ++nt) {
            const int ncol = n0 + wn + nt * 16 + fr;
            const int h = ncol >> 6, d = ncol & 63;
#pragma unroll
            for (int r = 0; r < 4; ++r) {
                const int mm = m0 + wm + mt * 16 + qd * 4 + r;
                const int b = mm >> 11, t = mm & (T_ - 1);
                const int bh = b * H_ + h;
                const size_t off = ((size_t)bh * T_ + t) * D_ + d;
                const float val = acc[mt][nt][r];
                if (which == 0)      qb[off]   = f2bf(val);
                else if (which == 1) kout[off] = val;
                else {
                    vout[off] = val;
                    vbt[((size_t)bh * D_ + d) * T_ + t] = f2bf(val);
                }
            }
        }
    }
}

// ---------------------------------------------------------------------------
// Output projection: out = attb @ Wo + bo (bf16 MFMA, fp32 out)
// ---------------------------------------------------------------------------
__global__ __launch_bounds__(256)
void gemm_o(const unsigned short* __restrict__ ab, const unsigned short* __restrict__ wot,
            const float* __restrict__ bo, float* __restrict__ out)
{
    __shared__ unsigned short As[128 * 32];
    __shared__ unsigned short Bs[128 * 32];

    const int tid = threadIdx.x;
    const int n0 = blockIdx.x * 128;
    const int m0 = blockIdx.y * 128;

    const int lane = tid & 63, w = tid >> 6;
    const int wm = (w >> 1) * 64, wn = (w & 1) * 64;
    const int fr = lane & 15, qd = lane >> 4;

    const int c0 = tid, c1 = tid + 256;
    const int ar0 = c0 >> 2, ak0 = (c0 & 3) * 8;
    const int ar1 = c1 >> 2, ak1 = (c1 & 3) * 8;

    f32x4 acc[4][4] = {};

    for (int k0 = 0; k0 < C_; k0 += 32) {
        __builtin_amdgcn_global_load_lds((gaddr_t*)(ab + (size_t)(m0 + ar0) * C_ + k0 + ak0),
                                         (laddr_t*)((char*)As + c0 * 16), 16, 0, 0);
        __builtin_amdgcn_global_load_lds((gaddr_t*)(ab + (size_t)(m0 + ar1) * C_ + k0 + ak1),
                                         (laddr_t*)((char*)As + c1 * 16), 16, 0, 0);
        __builtin_amdgcn_global_load_lds((gaddr_t*)(wot + (size_t)(n0 + ar0) * C_ + k0 + ak0),
                                         (laddr_t*)((char*)Bs + c0 * 16), 16, 0, 0);
        __builtin_amdgcn_global_load_lds((gaddr_t*)(wot + (size_t)(n0 + ar1) * C_ + k0 + ak1),
                                         (laddr_t*)((char*)Bs + c1 * 16), 16, 0, 0);
        __syncthreads();

        bf16x8 af[4], bfv[4];
#pragma unroll
        for (int mt = 0; mt < 4; ++mt)
            af[mt] = *(const bf16x8*)&As[(wm + mt * 16 + fr) * 32 + qd * 8];
#pragma unroll
        for (int nt = 0; nt < 4; ++nt)
            bfv[nt] = *(const bf16x8*)&Bs[(wn + nt * 16 + fr) * 32 + qd * 8];
#pragma unroll
        for (int mt = 0; mt < 4; ++mt)
#pragma unroll
            for (int nt = 0; nt < 4; ++nt)
                acc[mt][nt] = __builtin_amdgcn_mfma_f32_16x16x32_bf16(
                    af[mt], bfv[nt], acc[mt][nt], 0, 0, 0);
        __syncthreads();
    }

#pragma unroll
    for (int mt = 0; mt < 4; ++mt) {
#pragma unroll
        for (int nt = 0; nt < 4; ++nt) {
            const int ncol = n0 + wn + nt * 16 + fr;
            const float bb = bo[ncol];
#pragma unroll
            for (int r = 0; r < 4; ++r) {
                const int mm = m0 + wm + mt * 16 + qd * 4 + r;
                out[(size_t)mm * C_ + ncol] = acc[mt][nt][r] + bb;
            }
        }
    }
}

// ---------------------------------------------------------------------------
// MFMA flash attention. One wave = 16 q-rows, fully independent (no barrier).
// Block = 4 waves covering a 64-row q-tile; pairing (qt, 31-qt) -> 33 iters.
// Q bf16 A-frags in registers; K fp32 (inline cvt_pk->bf16), prefetched 1 jt
// ahead; V bf16 transposed (B,H,D,T) B-frags; P via wave-private LDS tile.
// ---------------------------------------------------------------------------
__global__ __launch_bounds__(256)
void attn_mfma(const unsigned short* __restrict__ qb, const float* __restrict__ kf,
               const unsigned short* __restrict__ vt, unsigned short* __restrict__ attb)
{
    __shared__ __hip_bfloat16 Pt[4][16 * 80];   // per-wave 16x64, stride 80

    const int tid = threadIdx.x;
    const int lane = tid & 63, w = tid >> 6;
    const int fr = lane & 15, qd = lane >> 4;
    const int bh = blockIdx.y, b = bh >> 4, h = bh & 15;
    __hip_bfloat16* Pw = Pt[w];

    const unsigned short* qB = qb + (size_t)bh * T_ * D_;
    const float*          kB = kf + (size_t)bh * T_ * D_;
    const unsigned short* vB = vt + (size_t)bh * D_ * T_;

    for (int rep = 0; rep < 2; ++rep) {
        const int qt = rep ? (31 - (int)blockIdx.x) : (int)blockIdx.x;
        const int qr0 = qt * 64 + w * 16;

        bf16x8 aq[2];
        aq[0] = *(const bf16x8*)(qB + (size_t)(qr0 + fr) * D_ + qd * 8);
        aq[1] = *(const bf16x8*)(qB + (size_t)(qr0 + fr) * D_ + 32 + qd * 8);

        f32x4 acc_o[4] = {};
        float m_i[4], l_i[4];
#pragma unroll
        for (int r = 0; r < 4; ++r) { m_i[r] = -1e30f; l_i[r] = 0.0f; }

        float4 kc[8][2];   // prefetched K frags (fp32), [nt*2+k0][half]
#pragma unroll
        for (int q8 = 0; q8 < 8; ++q8) {
            const float* p = kB + (size_t)((q8 >> 1) * 16 + fr) * D_ + (q8 & 1) * 32 + qd * 8;
            kc[q8][0] = *(const float4*)p;
            kc[q8][1] = *(const float4*)(p + 4);
        }

        for (int jt = 0; jt <= qt; ++jt) {
            // convert prefetched K to bf16 fragments
            bf16x8 bk[8];
#pragma unroll
            for (int q8 = 0; q8 < 8; ++q8) bk[q8] = cvt8(kc[q8][0], kc[q8][1]);

            // S = Q K^T
            f32x4 s4[4] = {};
#pragma unroll
            for (int nt = 0; nt < 4; ++nt) {
                s4[nt] = __builtin_amdgcn_mfma_f32_16x16x32_bf16(aq[0], bk[nt * 2 + 0], s4[nt], 0, 0, 0);
                s4[nt] = __builtin_amdgcn_mfma_f32_16x16x32_bf16(aq[1], bk[nt * 2 + 1], s4[nt], 0, 0, 0);
            }

            // V frags for this jt (used after softmax -> latency hidden)
            bf16x8 bv[8];
#pragma unroll
            for (int q8 = 0; q8 < 8; ++q8)
                bv[q8] = *(const bf16x8*)(vB + (size_t)((q8 >> 1) * 16 + fr) * T_
                                          + jt * 64 + (q8 & 1) * 32 + qd * 8);

            // prefetch K for next jt (dup of last iter is harmless)
            const int jn = (jt < qt) ? jt + 1 : jt;
#pragma unroll
            for (int q8 = 0; q8 < 8; ++q8) {
                const float* p = kB + (size_t)(jn * 64 + (q8 >> 1) * 16 + fr) * D_
                                 + (q8 & 1) * 32 + qd * 8;
                kc[q8][0] = *(const float4*)p;
                kc[q8][1] = *(const float4*)(p + 4);
            }

            // scale + causal mask (C layout: row=qd*4+r, col=nt*16+fr in-tile)
            const float sc = 0.125f;   // 1/sqrt(64)
            if (jt == qt) {
#pragma unroll
                for (int nt = 0; nt < 4; ++nt)
#pragma unroll
                for (int r = 0; r < 4; ++r) {
                    const int col = nt * 16 + fr;
                    const int row = w * 16 + qd * 4 + r;
                    s4[nt][r] = (col <= row) ? s4[nt][r] * sc : -1e30f;
                }
            } else {
#pragma unroll
                for (int nt = 0; nt < 4; ++nt)
#pragma unroll
                for (int r = 0; r < 4; ++r) s4[nt][r] *= sc;
            }

            // online softmax: each row's 16 cols live in lanes fr=0..15 (same qd)
#pragma unroll
            for (int r = 0; r < 4; ++r) {
                float mx = fmaxf(fmaxf(s4[0][r], s4[1][r]), fmaxf(s4[2][r], s4[3][r]));
                mx = fmaxf(mx, __shfl_xor(mx, 1, 16));
                mx = fmaxf(mx, __shfl_xor(mx, 2, 16));
                mx = fmaxf(mx, __shfl_xor(mx, 4, 16));
                mx = fmaxf(mx, __shfl_xor(mx, 8, 16));
                const float mnew = fmaxf(m_i[r], mx);
                const float alpha = __expf(m_i[r] - mnew);
                m_i[r] = mnew;
                float rs = 0.0f;
#pragma unroll
                for (int nt = 0; nt < 4; ++nt) {
                    const float pv = __expf(s4[nt][r] - mnew);
                    s4[nt][r] = pv;
                    rs += pv;
                }
                rs += __shfl_xor(rs, 1, 16);
                rs += __shfl_xor(rs, 2, 16);
                rs += __shfl_xor(rs, 4, 16);
                rs += __shfl_xor(rs, 8, 16);
                l_i[r] = l_i[r] * alpha + rs;
#pragma unroll
                for (int nt = 0; nt < 4; ++nt) acc_o[nt][r] *= alpha;
            }

            // P: C-layout -> A-layout via wave-private LDS (stride 80: 2-way max)
#pragma unroll
            for (int nt = 0; nt < 4; ++nt) {
                __hip_bfloat162 h01 = __float22bfloat162_rn(make_float2(s4[nt][0], s4[nt][1]));
                __hip_bfloat162 h23 = __float22bfloat162_rn(make_float2(s4[nt][2], s4[nt][3]));
                const int c = nt * 16 + fr;
                Pw[(qd * 4 + 0) * 80 + c] = h01.x;
                Pw[(qd * 4 + 1) * 80 + c] = h01.y;
                Pw[(qd * 4 + 2) * 80 + c] = h23.x;
                Pw[(qd * 4 + 3) * 80 + c] = h23.y;
            }
            bf16x8 ap0 = *(const bf16x8*)&Pw[fr * 80 + qd * 8];
            bf16x8 ap1 = *(const bf16x8*)&Pw[fr * 80 + 32 + qd * 8];

            // O += P V
#pragma unroll
            for (int nt = 0; nt < 4; ++nt) {
                acc_o[nt] = __builtin_amdgcn_mfma_f32_16x16x32_bf16(ap0, bv[nt * 2 + 0], acc_o[nt], 0, 0, 0);
                acc_o[nt] = __builtin_amdgcn_mfma_f32_16x16x32_bf16(ap1, bv[nt * 2 + 1], acc_o[nt], 0, 0, 0);
            }
        }

        // epilogue: O /= l, write bf16 (B,T,C)
#pragma unroll
        for (int r = 0; r < 4; ++r) {
            const float inv = 1.0f / l_i[r];
            unsigned short* op = attb + ((size_t)b * T_ + qr0 + qd * 4 + r) * C_ + h * 64;
#pragma unroll
            for (int nt = 0; nt < 4; ++nt)
                op[nt * 16 + fr] = f2bf(acc_o[nt][r] * inv);
        }
    }
}

// ---------------------------------------------------------------------------
extern "C" void kernel_launch(void* const* d_in, const int* in_sizes, int n_in,
                              void* d_out, int out_size, void* d_ws, size_t ws_size,
                              hipStream_t stream)
{
    (void)in_sizes; (void)n_in; (void)out_size; (void)ws_size;
    const float* x  = (const float*)d_in[0];
    const float* Wq = (const float*)d_in[1];
    const float* Wk = (const float*)d_in[2];
    const float* Wv = (const float*)d_in[3];
    const float* Wo = (const float*)d_in[4];
    const float* bo = (const float*)d_in[5];

    float* out  = (float*)d_out;                       // (B,T,C)
    float* kout = out  + (size_t)M_ * C_;              // (B,H,T,D) fp32
    float* vout = kout + (size_t)B_ * H_ * T_ * D_;    // (B,H,T,D) fp32

    // ws (32 MB): xb(8) | wtb(8) | qb(8) | vbt(8); attb aliases xb (dead then)
    unsigned short* xb   = (unsigned short*)d_ws;
    unsigned short* wtb  = xb  + (size_t)M_ * C_;
    unsigned short* qb   = wtb + (size_t)4 * C_ * C_;
    unsigned short* vbt  = qb  + (size_t)M_ * C_;
    unsigned short* attb = xb;

    cast_x<<<1024, 256, 0, stream>>>(x, xb, (M_ * C_) / 4);
    tcast_w<<<dim3(16, 16, 4), 256, 0, stream>>>(Wq, Wk, Wv, Wo, wtb);

    gemm_qkv<<<dim3(24, M_ / 128), 256, 0, stream>>>(xb, wtb, qb, kout, vout, vbt);

    attn_mfma<<<dim3(16, B_ * H_), 256, 0, stream>>>(qb, kout, vbt, attb);

    gemm_o<<<dim3(8, M_ / 128), 256, 0, stream>>>(attb, wtb + (size_t)3 * C_ * C_, bo, out);
}

// Round 4
// 309.635 us; speedup vs baseline: 3.9376x; 1.1604x over previous
//
#include <hip/hip_runtime.h>
#include <hip/hip_bf16.h>

constexpr int B_ = 2;
constexpr int T_ = 2048;
constexpr int C_ = 1024;
constexpr int H_ = 16;
constexpr int D_ = 64;
constexpr int M_ = B_ * T_;   // 4096 rows

typedef __attribute__((ext_vector_type(8))) short bf16x8;   // 8 bf16 = 4 VGPRs
typedef __attribute__((ext_vector_type(4))) float f32x4;
typedef const __attribute__((address_space(1))) void gaddr_t;
typedef __attribute__((address_space(3))) void laddr_t;

__device__ __forceinline__ unsigned short f2bf(float f) {   // fp32 -> bf16 RNE
    unsigned u = __float_as_uint(f);
    return (unsigned short)((u + 0x7fffu + ((u >> 16) & 1u)) >> 16);
}

union BF8 { bf16x8 v; __hip_bfloat162 h[4]; };

__device__ __forceinline__ bf16x8 cvt8(const float4 a, const float4 b) {
    BF8 r;
    r.h[0] = __float22bfloat162_rn(make_float2(a.x, a.y));
    r.h[1] = __float22bfloat162_rn(make_float2(a.z, a.w));
    r.h[2] = __float22bfloat162_rn(make_float2(b.x, b.y));
    r.h[3] = __float22bfloat162_rn(make_float2(b.z, b.w));
    return r.v;
}

// ---------------------------------------------------------------------------
// x (fp32) -> xb (bf16), flat
// ---------------------------------------------------------------------------
__global__ __launch_bounds__(256)
void cast_x(const float* __restrict__ x, unsigned short* __restrict__ xb, int n4)
{
    for (int i = blockIdx.x * 256 + threadIdx.x; i < n4; i += gridDim.x * 256) {
        float4 v = ((const float4*)x)[i];
        union { __hip_bfloat162 h[2]; ushort4 u; } o;
        o.h[0] = __float22bfloat162_rn(make_float2(v.x, v.y));
        o.h[1] = __float22bfloat162_rn(make_float2(v.z, v.w));
        ((ushort4*)xb)[i] = o.u;
    }
}

// ---------------------------------------------------------------------------
// W (K x N fp32, row-major) -> Wt (N x K bf16, row-major) for 4 weights.
// ---------------------------------------------------------------------------
__global__ __launch_bounds__(256)
void tcast_w(const float* __restrict__ Wq, const float* __restrict__ Wk,
             const float* __restrict__ Wv, const float* __restrict__ Wo,
             unsigned short* __restrict__ wtb)
{
    __shared__ float tile[64][65];
    const int z = blockIdx.z;
    const float* W = (z == 0) ? Wq : (z == 1) ? Wk : (z == 2) ? Wv : Wo;
    unsigned short* O = wtb + (size_t)z * C_ * C_;

    const int tid = threadIdx.x;
    const int n0 = blockIdx.x * 64, k0 = blockIdx.y * 64;
    const int r = tid >> 4, c4 = (tid & 15) * 4;

#pragma unroll
    for (int i = 0; i < 4; ++i) {
        const int kk = i * 16 + r;
        float4 v = *(const float4*)(W + (size_t)(k0 + kk) * C_ + n0 + c4);
        tile[c4 + 0][kk] = v.x;
        tile[c4 + 1][kk] = v.y;
        tile[c4 + 2][kk] = v.z;
        tile[c4 + 3][kk] = v.w;
    }
    __syncthreads();
#pragma unroll
    for (int i = 0; i < 4; ++i) {
        const int nn = i * 16 + r;
        ushort4 o;
        o.x = f2bf(tile[nn][c4 + 0]);
        o.y = f2bf(tile[nn][c4 + 1]);
        o.z = f2bf(tile[nn][c4 + 2]);
        o.w = f2bf(tile[nn][c4 + 3]);
        *(ushort4*)(O + (size_t)(n0 + nn) * C_ + k0 + c4) = o;
    }
}

// ---------------------------------------------------------------------------
// Fused QKV bf16 MFMA GEMM (128x128 tile, BK=32, global_load_lds 16B).
// q -> qb (bf16); k -> kout (fp32) [+ kb bf16 if WRITE_KB]; v -> vout (fp32).
// All epilogue stores are lane-coalesced (d = fr). V-transpose moved to a
// dedicated kernel (the old strided scalar scatter was the gemm bottleneck).
// ---------------------------------------------------------------------------
template<int WRITE_KB>
__global__ __launch_bounds__(256)
void gemm_qkv(const unsigned short* __restrict__ xb, const unsigned short* __restrict__ wtb,
              unsigned short* __restrict__ qb, float* __restrict__ kout,
              float* __restrict__ vout, unsigned short* __restrict__ kb)
{
    __shared__ unsigned short As[128 * 32];
    __shared__ unsigned short Bs[128 * 32];

    const int tid = threadIdx.x;
    const int which = blockIdx.x >> 3;             // 0=q 1=k 2=v
    const int n0 = (blockIdx.x & 7) * 128;
    const int m0 = blockIdx.y * 128;
    const unsigned short* wt = wtb + (size_t)which * C_ * C_;

    const int lane = tid & 63, w = tid >> 6;
    const int wm = (w >> 1) * 64, wn = (w & 1) * 64;
    const int fr = lane & 15, qd = lane >> 4;

    const int c0 = tid, c1 = tid + 256;
    const int ar0 = c0 >> 2, ak0 = (c0 & 3) * 8;
    const int ar1 = c1 >> 2, ak1 = (c1 & 3) * 8;

    f32x4 acc[4][4] = {};

    for (int k0 = 0; k0 < C_; k0 += 32) {
        __builtin_amdgcn_global_load_lds((gaddr_t*)(xb + (size_t)(m0 + ar0) * C_ + k0 + ak0),
                                         (laddr_t*)((char*)As + c0 * 16), 16, 0, 0);
        __builtin_amdgcn_global_load_lds((gaddr_t*)(xb + (size_t)(m0 + ar1) * C_ + k0 + ak1),
                                         (laddr_t*)((char*)As + c1 * 16), 16, 0, 0);
        __builtin_amdgcn_global_load_lds((gaddr_t*)(wt + (size_t)(n0 + ar0) * C_ + k0 + ak0),
                                         (laddr_t*)((char*)Bs + c0 * 16), 16, 0, 0);
        __builtin_amdgcn_global_load_lds((gaddr_t*)(wt + (size_t)(n0 + ar1) * C_ + k0 + ak1),
                                         (laddr_t*)((char*)Bs + c1 * 16), 16, 0, 0);
        __syncthreads();

        bf16x8 af[4], bfv[4];
#pragma unroll
        for (int mt = 0; mt < 4; ++mt)
            af[mt] = *(const bf16x8*)&As[(wm + mt * 16 + fr) * 32 + qd * 8];
#pragma unroll
        for (int nt = 0; nt < 4; ++nt)
            bfv[nt] = *(const bf16x8*)&Bs[(wn + nt * 16 + fr) * 32 + qd * 8];
#pragma unroll
        for (int mt = 0; mt < 4; ++mt)
#pragma unroll
            for (int nt = 0; nt < 4; ++nt)
                acc[mt][nt] = __builtin_amdgcn_mfma_f32_16x16x32_bf16(
                    af[mt], bfv[nt], acc[mt][nt], 0, 0, 0);
        __syncthreads();
    }

    // C/D layout: col = lane&15, row = (lane>>4)*4 + reg
#pragma unroll
    for (int mt = 0; mt < 4; ++mt) {
#pragma unroll
        for (int nt = 0; nt < 4; ++nt) {
            const int ncol = n0 + wn + nt * 16 + fr;
            const int h = ncol >> 6, d = ncol & 63;
#pragma unroll
            for (int r = 0; r < 4; ++r) {
                const int mm = m0 + wm + mt * 16 + qd * 4 + r;
                const int b = mm >> 11, t = mm & (T_ - 1);
                const int bh = b * H_ + h;
                const size_t off = ((size_t)bh * T_ + t) * D_ + d;
                const float val = acc[mt][nt][r];
                if (which == 0)      qb[off]   = f2bf(val);
                else if (which == 1) {
                    kout[off] = val;
                    if (WRITE_KB) kb[off] = f2bf(val);
                } else               vout[off] = val;
            }
        }
    }
}

// ---------------------------------------------------------------------------
// vout (B,H,T,D fp32) -> vbt (B,H,D,T bf16) via LDS tile, coalesced both ways.
// ---------------------------------------------------------------------------
__global__ __launch_bounds__(256)
void transpose_v(const float* __restrict__ v, unsigned short* __restrict__ vbt)
{
    __shared__ unsigned short tile[64 * 66];
    const int tid = threadIdx.x;
    const int bh = blockIdx.y, t0 = blockIdx.x * 64;
    const float* vB = v + ((size_t)bh * T_ + t0) * D_;

    const int r = tid >> 4, c4 = (tid & 15) * 4;
#pragma unroll
    for (int i = 0; i < 4; ++i) {
        const int tt = i * 16 + r;
        float4 x4 = *(const float4*)(vB + tt * D_ + c4);
        tile[(c4 + 0) * 66 + tt] = f2bf(x4.x);
        tile[(c4 + 1) * 66 + tt] = f2bf(x4.y);
        tile[(c4 + 2) * 66 + tt] = f2bf(x4.z);
        tile[(c4 + 3) * 66 + tt] = f2bf(x4.w);
    }
    __syncthreads();
#pragma unroll
    for (int i = 0; i < 4; ++i) {
        const int d = i * 16 + r;
        ushort4 o;
        o.x = tile[d * 66 + c4 + 0];
        o.y = tile[d * 66 + c4 + 1];
        o.z = tile[d * 66 + c4 + 2];
        o.w = tile[d * 66 + c4 + 3];
        *(ushort4*)(vbt + ((size_t)bh * D_ + d) * T_ + t0 + c4) = o;
    }
}

// ---------------------------------------------------------------------------
// Output projection: out = attb @ Wo + bo (bf16 MFMA, fp32 out)
// ---------------------------------------------------------------------------
__global__ __launch_bounds__(256)
void gemm_o(const unsigned short* __restrict__ ab, const unsigned short* __restrict__ wot,
            const float* __restrict__ bo, float* __restrict__ out)
{
    __shared__ unsigned short As[128 * 32];
    __shared__ unsigned short Bs[128 * 32];

    const int tid = threadIdx.x;
    const int n0 = blockIdx.x * 128;
    const int m0 = blockIdx.y * 128;

    const int lane = tid & 63, w = tid >> 6;
    const int wm = (w >> 1) * 64, wn = (w & 1) * 64;
    const int fr = lane & 15, qd = lane >> 4;

    const int c0 = tid, c1 = tid + 256;
    const int ar0 = c0 >> 2, ak0 = (c0 & 3) * 8;
    const int ar1 = c1 >> 2, ak1 = (c1 & 3) * 8;

    f32x4 acc[4][4] = {};

    for (int k0 = 0; k0 < C_; k0 += 32) {
        __builtin_amdgcn_global_load_lds((gaddr_t*)(ab + (size_t)(m0 + ar0) * C_ + k0 + ak0),
                                         (laddr_t*)((char*)As + c0 * 16), 16, 0, 0);
        __builtin_amdgcn_global_load_lds((gaddr_t*)(ab + (size_t)(m0 + ar1) * C_ + k0 + ak1),
                                         (laddr_t*)((char*)As + c1 * 16), 16, 0, 0);
        __builtin_amdgcn_global_load_lds((gaddr_t*)(wot + (size_t)(n0 + ar0) * C_ + k0 + ak0),
                                         (laddr_t*)((char*)Bs + c0 * 16), 16, 0, 0);
        __builtin_amdgcn_global_load_lds((gaddr_t*)(wot + (size_t)(n0 + ar1) * C_ + k0 + ak1),
                                         (laddr_t*)((char*)Bs + c1 * 16), 16, 0, 0);
        __syncthreads();

        bf16x8 af[4], bfv[4];
#pragma unroll
        for (int mt = 0; mt < 4; ++mt)
            af[mt] = *(const bf16x8*)&As[(wm + mt * 16 + fr) * 32 + qd * 8];
#pragma unroll
        for (int nt = 0; nt < 4; ++nt)
            bfv[nt] = *(const bf16x8*)&Bs[(wn + nt * 16 + fr) * 32 + qd * 8];
#pragma unroll
        for (int mt = 0; mt < 4; ++mt)
#pragma unroll
            for (int nt = 0; nt < 4; ++nt)
                acc[mt][nt] = __builtin_amdgcn_mfma_f32_16x16x32_bf16(
                    af[mt], bfv[nt], acc[mt][nt], 0, 0, 0);
        __syncthreads();
    }

#pragma unroll
    for (int mt = 0; mt < 4; ++mt) {
#pragma unroll
        for (int nt = 0; nt < 4; ++nt) {
            const int ncol = n0 + wn + nt * 16 + fr;
            const float bb = bo[ncol];
#pragma unroll
            for (int r = 0; r < 4; ++r) {
                const int mm = m0 + wm + mt * 16 + qd * 4 + r;
                out[(size_t)mm * C_ + ncol] = acc[mt][nt][r] + bb;
            }
        }
    }
}

// ---------------------------------------------------------------------------
// MFMA flash attention v2.
// Grid 1024 blocks; XCD-aware swizzle: xcd = blk&7, all 32 q-tiles of a bh
// stay on one XCD (4 bh/XCD -> K+V+Q working set ~3 MB < 4 MiB L2).
// High-qt blocks launch first (descending qt) so the tail is short blocks.
// One wave = 16 q-rows, no barriers; K bf16 (KB) or fp32+cvt fallback;
// K prefetched one jt ahead; V from transposed bf16 vbt; P via wave-private
// LDS tile (stride 72 = 2-way conflicts = free).
// ---------------------------------------------------------------------------
template<bool KB>
__global__ __launch_bounds__(256)
void attn_mfma(const unsigned short* __restrict__ qb, const float* __restrict__ kf,
               const unsigned short* __restrict__ kbp, const unsigned short* __restrict__ vt,
               unsigned short* __restrict__ attb)
{
    __shared__ alignas(16) unsigned short Pt[4][16 * 72];

    const int tid = threadIdx.x;
    const int lane = tid & 63, w = tid >> 6;
    const int fr = lane & 15, qd = lane >> 4;

    const int blk = blockIdx.x;
    const int xcd = blk & 7, within = blk >> 3;      // within: 0..127
    const int bh = xcd * 4 + (within & 3);           // 4 heads per XCD slot
    const int qt = 31 - (within >> 2);               // descending qt
    const int b = bh >> 4, h = bh & 15;

    unsigned short* Pw = Pt[w];
    const unsigned short* qB  = qb  + (size_t)bh * T_ * D_;
    const float*          kB  = kf  + (size_t)bh * T_ * D_;
    const unsigned short* kbB = kbp + (size_t)bh * T_ * D_;
    const unsigned short* vB  = vt  + (size_t)bh * D_ * T_;

    const int qr0 = qt * 64 + w * 16;

    bf16x8 aq[2];
    aq[0] = *(const bf16x8*)(qB + (size_t)(qr0 + fr) * D_ + qd * 8);
    aq[1] = *(const bf16x8*)(qB + (size_t)(qr0 + fr) * D_ + 32 + qd * 8);

    f32x4 acc_o[4] = {};
    float m_i[4], l_i[4];
#pragma unroll
    for (int r = 0; r < 4; ++r) { m_i[r] = -1e30f; l_i[r] = 0.0f; }

    auto loadK = [&](int j, bf16x8* dst) {
#pragma unroll
        for (int q8 = 0; q8 < 8; ++q8) {
            const size_t row = (size_t)(j * 64 + (q8 >> 1) * 16 + fr);
            const int dof = (q8 & 1) * 32 + qd * 8;
            if (KB) {
                dst[q8] = *(const bf16x8*)(kbB + row * D_ + dof);
            } else {
                const float* p = kB + row * D_ + dof;
                dst[q8] = cvt8(*(const float4*)p, *(const float4*)(p + 4));
            }
        }
    };

    bf16x8 bk[8];
    loadK(0, bk);

    for (int jt = 0; jt <= qt; ++jt) {
        // V frags for this jt
        bf16x8 bv[8];
#pragma unroll
        for (int q8 = 0; q8 < 8; ++q8)
            bv[q8] = *(const bf16x8*)(vB + (size_t)((q8 >> 1) * 16 + fr) * T_
                                      + jt * 64 + (q8 & 1) * 32 + qd * 8);

        // prefetch next K
        bf16x8 bkn[8];
        if (jt < qt) loadK(jt + 1, bkn);

        // S = Q K^T
        f32x4 s4[4] = {};
#pragma unroll
        for (int nt = 0; nt < 4; ++nt) {
            s4[nt] = __builtin_amdgcn_mfma_f32_16x16x32_bf16(aq[0], bk[nt * 2 + 0], s4[nt], 0, 0, 0);
            s4[nt] = __builtin_amdgcn_mfma_f32_16x16x32_bf16(aq[1], bk[nt * 2 + 1], s4[nt], 0, 0, 0);
        }

        // scale + causal mask (C layout: row=qd*4+r, col=nt*16+fr in-tile)
        const float sc = 0.125f;   // 1/sqrt(64)
        if (jt == qt) {
#pragma unroll
            for (int nt = 0; nt < 4; ++nt)
#pragma unroll
            for (int r = 0; r < 4; ++r) {
                const int col = nt * 16 + fr;
                const int row = w * 16 + qd * 4 + r;
                s4[nt][r] = (col <= row) ? s4[nt][r] * sc : -1e30f;
            }
        } else {
#pragma unroll
            for (int nt = 0; nt < 4; ++nt)
#pragma unroll
            for (int r = 0; r < 4; ++r) s4[nt][r] *= sc;
        }

        // online softmax: each row's 16 cols live in lanes fr=0..15 (same qd)
#pragma unroll
        for (int r = 0; r < 4; ++r) {
            float mx = fmaxf(fmaxf(s4[0][r], s4[1][r]), fmaxf(s4[2][r], s4[3][r]));
            mx = fmaxf(mx, __shfl_xor(mx, 1, 16));
            mx = fmaxf(mx, __shfl_xor(mx, 2, 16));
            mx = fmaxf(mx, __shfl_xor(mx, 4, 16));
            mx = fmaxf(mx, __shfl_xor(mx, 8, 16));
            const float mnew = fmaxf(m_i[r], mx);
            const float alpha = __expf(m_i[r] - mnew);
            m_i[r] = mnew;
            float rs = 0.0f;
#pragma unroll
            for (int nt = 0; nt < 4; ++nt) {
                const float pv = __expf(s4[nt][r] - mnew);
                s4[nt][r] = pv;
                rs += pv;
            }
            rs += __shfl_xor(rs, 1, 16);
            rs += __shfl_xor(rs, 2, 16);
            rs += __shfl_xor(rs, 4, 16);
            rs += __shfl_xor(rs, 8, 16);
            l_i[r] = l_i[r] * alpha + rs;
#pragma unroll
            for (int nt = 0; nt < 4; ++nt) acc_o[nt][r] *= alpha;
        }

        // P: C-layout -> A-layout via wave-private LDS (stride 72)
#pragma unroll
        for (int nt = 0; nt < 4; ++nt) {
            __hip_bfloat162 h01 = __float22bfloat162_rn(make_float2(s4[nt][0], s4[nt][1]));
            __hip_bfloat162 h23 = __float22bfloat162_rn(make_float2(s4[nt][2], s4[nt][3]));
            const int c = nt * 16 + fr;
            Pw[(qd * 4 + 0) * 72 + c] = *(unsigned short*)&h01.x;
            Pw[(qd * 4 + 1) * 72 + c] = *(unsigned short*)&h01.y;
            Pw[(qd * 4 + 2) * 72 + c] = *(unsigned short*)&h23.x;
            Pw[(qd * 4 + 3) * 72 + c] = *(unsigned short*)&h23.y;
        }
        bf16x8 ap0 = *(const bf16x8*)&Pw[fr * 72 + qd * 8];
        bf16x8 ap1 = *(const bf16x8*)&Pw[fr * 72 + 32 + qd * 8];

        // O += P V
#pragma unroll
        for (int nt = 0; nt < 4; ++nt) {
            acc_o[nt] = __builtin_amdgcn_mfma_f32_16x16x32_bf16(ap0, bv[nt * 2 + 0], acc_o[nt], 0, 0, 0);
            acc_o[nt] = __builtin_amdgcn_mfma_f32_16x16x32_bf16(ap1, bv[nt * 2 + 1], acc_o[nt], 0, 0, 0);
        }

        if (jt < qt) {
#pragma unroll
            for (int q8 = 0; q8 < 8; ++q8) bk[q8] = bkn[q8];
        }
    }

    // epilogue: O /= l, write bf16 (B,T,C)
#pragma unroll
    for (int r = 0; r < 4; ++r) {
        const float inv = 1.0f / l_i[r];
        unsigned short* op = attb + ((size_t)b * T_ + qr0 + qd * 4 + r) * C_ + h * 64;
#pragma unroll
        for (int nt = 0; nt < 4; ++nt)
            op[nt * 16 + fr] = f2bf(acc_o[nt][r] * inv);
    }
}

// ---------------------------------------------------------------------------
extern "C" void kernel_launch(void* const* d_in, const int* in_sizes, int n_in,
                              void* d_out, int out_size, void* d_ws, size_t ws_size,
                              hipStream_t stream)
{
    (void)in_sizes; (void)n_in; (void)out_size;
    const float* x  = (const float*)d_in[0];
    const float* Wq = (const float*)d_in[1];
    const float* Wk = (const float*)d_in[2];
    const float* Wv = (const float*)d_in[3];
    const float* Wo = (const float*)d_in[4];
    const float* bo = (const float*)d_in[5];

    float* out  = (float*)d_out;                       // (B,T,C)
    float* kout = out  + (size_t)M_ * C_;              // (B,H,T,D) fp32
    float* vout = kout + (size_t)B_ * H_ * T_ * D_;    // (B,H,T,D) fp32

    // ws: xb(8M) | wtb(8M) | qb(8M) | vbt(8M) | kb(8M, optional); attb aliases xb
    unsigned short* xb   = (unsigned short*)d_ws;
    unsigned short* wtb  = xb  + (size_t)M_ * C_;
    unsigned short* qb   = wtb + (size_t)4 * C_ * C_;
    unsigned short* vbt  = qb  + (size_t)M_ * C_;
    unsigned short* kb   = vbt + (size_t)M_ * C_;
    unsigned short* attb = xb;
    const bool use_kb = ws_size >= (size_t)40 * 1024 * 1024;

    cast_x<<<1024, 256, 0, stream>>>(x, xb, (M_ * C_) / 4);
    tcast_w<<<dim3(16, 16, 4), 256, 0, stream>>>(Wq, Wk, Wv, Wo, wtb);

    if (use_kb)
        gemm_qkv<1><<<dim3(24, M_ / 128), 256, 0, stream>>>(xb, wtb, qb, kout, vout, kb);
    else
        gemm_qkv<0><<<dim3(24, M_ / 128), 256, 0, stream>>>(xb, wtb, qb, kout, vout, kb);

    transpose_v<<<dim3(T_ / 64, B_ * H_), 256, 0, stream>>>(vout, vbt);

    if (use_kb)
        attn_mfma<true><<<1024, 256, 0, stream>>>(qb, kout, kb, vbt, attb);
    else
        attn_mfma<false><<<1024, 256, 0, stream>>>(qb, kout, kb, vbt, attb);

    gemm_o<<<dim3(8, M_ / 128), 256, 0, stream>>>(attb, wtb + (size_t)3 * C_ * C_, bo, out);
}

// Round 5
// 294.286 us; speedup vs baseline: 4.1430x; 1.0522x over previous
//
#include <hip/hip_runtime.h>
#include <hip/hip_bf16.h>

constexpr int B_ = 2;
constexpr int T_ = 2048;
constexpr int C_ = 1024;
constexpr int H_ = 16;
constexpr int D_ = 64;
constexpr int M_ = B_ * T_;   // 4096 rows

typedef __attribute__((ext_vector_type(8))) short bf16x8;   // 8 bf16 = 4 VGPRs
typedef __attribute__((ext_vector_type(4))) float f32x4;
typedef const __attribute__((address_space(1))) void gaddr_t;
typedef __attribute__((address_space(3))) void laddr_t;

__device__ __forceinline__ unsigned short f2bf(float f) {   // fp32 -> bf16 RNE
    unsigned u = __float_as_uint(f);
    return (unsigned short)((u + 0x7fffu + ((u >> 16) & 1u)) >> 16);
}

union BF8 { bf16x8 v; __hip_bfloat162 h[4]; };

__device__ __forceinline__ bf16x8 cvt8(const float4 a, const float4 b) {
    BF8 r;
    r.h[0] = __float22bfloat162_rn(make_float2(a.x, a.y));
    r.h[1] = __float22bfloat162_rn(make_float2(a.z, a.w));
    r.h[2] = __float22bfloat162_rn(make_float2(b.x, b.y));
    r.h[3] = __float22bfloat162_rn(make_float2(b.z, b.w));
    return r.v;
}

// ---------------------------------------------------------------------------
// x (fp32) -> xb (bf16), flat
// ---------------------------------------------------------------------------
__global__ __launch_bounds__(256)
void cast_x(const float* __restrict__ x, unsigned short* __restrict__ xb, int n4)
{
    for (int i = blockIdx.x * 256 + threadIdx.x; i < n4; i += gridDim.x * 256) {
        float4 v = ((const float4*)x)[i];
        union { __hip_bfloat162 h[2]; ushort4 u; } o;
        o.h[0] = __float22bfloat162_rn(make_float2(v.x, v.y));
        o.h[1] = __float22bfloat162_rn(make_float2(v.z, v.w));
        ((ushort4*)xb)[i] = o.u;
    }
}

// ---------------------------------------------------------------------------
// W (K x N fp32, row-major) -> Wt (N x K bf16, row-major) for 4 weights.
// ---------------------------------------------------------------------------
__global__ __launch_bounds__(256)
void tcast_w(const float* __restrict__ Wq, const float* __restrict__ Wk,
             const float* __restrict__ Wv, const float* __restrict__ Wo,
             unsigned short* __restrict__ wtb)
{
    __shared__ float tile[64][65];
    const int z = blockIdx.z;
    const float* W = (z == 0) ? Wq : (z == 1) ? Wk : (z == 2) ? Wv : Wo;
    unsigned short* O = wtb + (size_t)z * C_ * C_;

    const int tid = threadIdx.x;
    const int n0 = blockIdx.x * 64, k0 = blockIdx.y * 64;
    const int r = tid >> 4, c4 = (tid & 15) * 4;

#pragma unroll
    for (int i = 0; i < 4; ++i) {
        const int kk = i * 16 + r;
        float4 v = *(const float4*)(W + (size_t)(k0 + kk) * C_ + n0 + c4);
        tile[c4 + 0][kk] = v.x;
        tile[c4 + 1][kk] = v.y;
        tile[c4 + 2][kk] = v.z;
        tile[c4 + 3][kk] = v.w;
    }
    __syncthreads();
#pragma unroll
    for (int i = 0; i < 4; ++i) {
        const int nn = i * 16 + r;
        ushort4 o;
        o.x = f2bf(tile[nn][c4 + 0]);
        o.y = f2bf(tile[nn][c4 + 1]);
        o.z = f2bf(tile[nn][c4 + 2]);
        o.w = f2bf(tile[nn][c4 + 3]);
        *(ushort4*)(O + (size_t)(n0 + nn) * C_ + k0 + c4) = o;
    }
}

// ---------------------------------------------------------------------------
// Fused QKV bf16 MFMA GEMM (128x128 tile, BK=32, global_load_lds 16B).
// q -> qb (bf16); k -> kout (fp32) [+ kb bf16 if WRITE_KB]; v -> vout (fp32).
// ---------------------------------------------------------------------------
template<int WRITE_KB>
__global__ __launch_bounds__(256)
void gemm_qkv(const unsigned short* __restrict__ xb, const unsigned short* __restrict__ wtb,
              unsigned short* __restrict__ qb, float* __restrict__ kout,
              float* __restrict__ vout, unsigned short* __restrict__ kb)
{
    __shared__ unsigned short As[128 * 32];
    __shared__ unsigned short Bs[128 * 32];

    const int tid = threadIdx.x;
    const int which = blockIdx.x >> 3;             // 0=q 1=k 2=v
    const int n0 = (blockIdx.x & 7) * 128;
    const int m0 = blockIdx.y * 128;
    const unsigned short* wt = wtb + (size_t)which * C_ * C_;

    const int lane = tid & 63, w = tid >> 6;
    const int wm = (w >> 1) * 64, wn = (w & 1) * 64;
    const int fr = lane & 15, qd = lane >> 4;

    const int c0 = tid, c1 = tid + 256;
    const int ar0 = c0 >> 2, ak0 = (c0 & 3) * 8;
    const int ar1 = c1 >> 2, ak1 = (c1 & 3) * 8;

    f32x4 acc[4][4] = {};

    for (int k0 = 0; k0 < C_; k0 += 32) {
        __builtin_amdgcn_global_load_lds((gaddr_t*)(xb + (size_t)(m0 + ar0) * C_ + k0 + ak0),
                                         (laddr_t*)((char*)As + c0 * 16), 16, 0, 0);
        __builtin_amdgcn_global_load_lds((gaddr_t*)(xb + (size_t)(m0 + ar1) * C_ + k0 + ak1),
                                         (laddr_t*)((char*)As + c1 * 16), 16, 0, 0);
        __builtin_amdgcn_global_load_lds((gaddr_t*)(wt + (size_t)(n0 + ar0) * C_ + k0 + ak0),
                                         (laddr_t*)((char*)Bs + c0 * 16), 16, 0, 0);
        __builtin_amdgcn_global_load_lds((gaddr_t*)(wt + (size_t)(n0 + ar1) * C_ + k0 + ak1),
                                         (laddr_t*)((char*)Bs + c1 * 16), 16, 0, 0);
        __syncthreads();

        bf16x8 af[4], bfv[4];
#pragma unroll
        for (int mt = 0; mt < 4; ++mt)
            af[mt] = *(const bf16x8*)&As[(wm + mt * 16 + fr) * 32 + qd * 8];
#pragma unroll
        for (int nt = 0; nt < 4; ++nt)
            bfv[nt] = *(const bf16x8*)&Bs[(wn + nt * 16 + fr) * 32 + qd * 8];
#pragma unroll
        for (int mt = 0; mt < 4; ++mt)
#pragma unroll
            for (int nt = 0; nt < 4; ++nt)
                acc[mt][nt] = __builtin_amdgcn_mfma_f32_16x16x32_bf16(
                    af[mt], bfv[nt], acc[mt][nt], 0, 0, 0);
        __syncthreads();
    }

    // C/D layout: col = lane&15, row = (lane>>4)*4 + reg
#pragma unroll
    for (int mt = 0; mt < 4; ++mt) {
#pragma unroll
        for (int nt = 0; nt < 4; ++nt) {
            const int ncol = n0 + wn + nt * 16 + fr;
            const int h = ncol >> 6, d = ncol & 63;
#pragma unroll
            for (int r = 0; r < 4; ++r) {
                const int mm = m0 + wm + mt * 16 + qd * 4 + r;
                const int b = mm >> 11, t = mm & (T_ - 1);
                const int bh = b * H_ + h;
                const size_t off = ((size_t)bh * T_ + t) * D_ + d;
                const float val = acc[mt][nt][r];
                if (which == 0)      qb[off]   = f2bf(val);
                else if (which == 1) {
                    kout[off] = val;
                    if (WRITE_KB) kb[off] = f2bf(val);
                } else               vout[off] = val;
            }
        }
    }
}

// ---------------------------------------------------------------------------
// vout (B,H,T,D fp32) -> vbt (B,H,D,T bf16) via LDS tile, coalesced both ways.
// ---------------------------------------------------------------------------
__global__ __launch_bounds__(256)
void transpose_v(const float* __restrict__ v, unsigned short* __restrict__ vbt)
{
    __shared__ unsigned short tile[64 * 66];
    const int tid = threadIdx.x;
    const int bh = blockIdx.y, t0 = blockIdx.x * 64;
    const float* vB = v + ((size_t)bh * T_ + t0) * D_;

    const int r = tid >> 4, c4 = (tid & 15) * 4;
#pragma unroll
    for (int i = 0; i < 4; ++i) {
        const int tt = i * 16 + r;
        float4 x4 = *(const float4*)(vB + tt * D_ + c4);
        tile[(c4 + 0) * 66 + tt] = f2bf(x4.x);
        tile[(c4 + 1) * 66 + tt] = f2bf(x4.y);
        tile[(c4 + 2) * 66 + tt] = f2bf(x4.z);
        tile[(c4 + 3) * 66 + tt] = f2bf(x4.w);
    }
    __syncthreads();
#pragma unroll
    for (int i = 0; i < 4; ++i) {
        const int d = i * 16 + r;
        ushort4 o;
        o.x = tile[d * 66 + c4 + 0];
        o.y = tile[d * 66 + c4 + 1];
        o.z = tile[d * 66 + c4 + 2];
        o.w = tile[d * 66 + c4 + 3];
        *(ushort4*)(vbt + ((size_t)bh * D_ + d) * T_ + t0 + c4) = o;
    }
}

// ---------------------------------------------------------------------------
// Output projection: out = attb @ Wo + bo (bf16 MFMA, fp32 out)
// ---------------------------------------------------------------------------
__global__ __launch_bounds__(256)
void gemm_o(const unsigned short* __restrict__ ab, const unsigned short* __restrict__ wot,
            const float* __restrict__ bo, float* __restrict__ out)
{
    __shared__ unsigned short As[128 * 32];
    __shared__ unsigned short Bs[128 * 32];

    const int tid = threadIdx.x;
    const int n0 = blockIdx.x * 128;
    const int m0 = blockIdx.y * 128;

    const int lane = tid & 63, w = tid >> 6;
    const int wm = (w >> 1) * 64, wn = (w & 1) * 64;
    const int fr = lane & 15, qd = lane >> 4;

    const int c0 = tid, c1 = tid + 256;
    const int ar0 = c0 >> 2, ak0 = (c0 & 3) * 8;
    const int ar1 = c1 >> 2, ak1 = (c1 & 3) * 8;

    f32x4 acc[4][4] = {};

    for (int k0 = 0; k0 < C_; k0 += 32) {
        __builtin_amdgcn_global_load_lds((gaddr_t*)(ab + (size_t)(m0 + ar0) * C_ + k0 + ak0),
                                         (laddr_t*)((char*)As + c0 * 16), 16, 0, 0);
        __builtin_amdgcn_global_load_lds((gaddr_t*)(ab + (size_t)(m0 + ar1) * C_ + k0 + ak1),
                                         (laddr_t*)((char*)As + c1 * 16), 16, 0, 0);
        __builtin_amdgcn_global_load_lds((gaddr_t*)(wot + (size_t)(n0 + ar0) * C_ + k0 + ak0),
                                         (laddr_t*)((char*)Bs + c0 * 16), 16, 0, 0);
        __builtin_amdgcn_global_load_lds((gaddr_t*)(wot + (size_t)(n0 + ar1) * C_ + k0 + ak1),
                                         (laddr_t*)((char*)Bs + c1 * 16), 16, 0, 0);
        __syncthreads();

        bf16x8 af[4], bfv[4];
#pragma unroll
        for (int mt = 0; mt < 4; ++mt)
            af[mt] = *(const bf16x8*)&As[(wm + mt * 16 + fr) * 32 + qd * 8];
#pragma unroll
        for (int nt = 0; nt < 4; ++nt)
            bfv[nt] = *(const bf16x8*)&Bs[(wn + nt * 16 + fr) * 32 + qd * 8];
#pragma unroll
        for (int mt = 0; mt < 4; ++mt)
#pragma unroll
            for (int nt = 0; nt < 4; ++nt)
                acc[mt][nt] = __builtin_amdgcn_mfma_f32_16x16x32_bf16(
                    af[mt], bfv[nt], acc[mt][nt], 0, 0, 0);
        __syncthreads();
    }

#pragma unroll
    for (int mt = 0; mt < 4; ++mt) {
#pragma unroll
        for (int nt = 0; nt < 4; ++nt) {
            const int ncol = n0 + wn + nt * 16 + fr;
            const float bb = bo[ncol];
#pragma unroll
            for (int r = 0; r < 4; ++r) {
                const int mm = m0 + wm + mt * 16 + qd * 4 + r;
                out[(size_t)mm * C_ + ncol] = acc[mt][nt][r] + bb;
            }
        }
    }
}

// ---------------------------------------------------------------------------
// MFMA flash attention v3 — transposed dataflow.
// S^T = K·Q^T  (K as A-frag, Q as B-frag): each lane owns 16 score cols of ONE
// q-row (q-row = lane&15) -> softmax reductions are in-lane + 2 shfls.
// O^T = V^T·P^T (V^T as A-frag from vbt, P as B-frag): O^T col = q-row ->
// alpha/l rescale fully in-lane, no transpose shuffles.
// P round-trip: 4x ds_write_b64 + 2x ds_read_b128 (wave-private, stride 72).
// Epilogue: O^T -> O via per-wave LDS transpose, coalesced dwordx4 stores.
// Grid 1024, XCD swizzle (bh pinned per CU), qt permutation {31-i, i, 23-i,
// 8+i} gives every CU exactly 66 iterations (perfect static balance).
// ---------------------------------------------------------------------------
template<bool KB>
__global__ __launch_bounds__(256)
void attn_mfma(const unsigned short* __restrict__ qb, const float* __restrict__ kf,
               const unsigned short* __restrict__ kbp, const unsigned short* __restrict__ vt,
               unsigned short* __restrict__ attb)
{
    __shared__ alignas(16) unsigned short Pt[4][16 * 72];

    const int tid = threadIdx.x;
    const int lane = tid & 63, w = tid >> 6;
    const int fr = lane & 15, qd = lane >> 4;

    const int blk = blockIdx.x;
    const int xcd = blk & 7, within = blk >> 3;      // within: 0..127
    const int bh = xcd * 4 + (within & 3);           // bh constant per CU slot
    const int j = within >> 2;                       // 0..31
    const int kk_ = j >> 3, ii_ = j & 7;
    const int qt = (kk_ == 0) ? (31 - ii_) : (kk_ == 1) ? ii_
                 : (kk_ == 2) ? (23 - ii_) : (8 + ii_);
    const int b = bh >> 4, h = bh & 15;

    unsigned short* Pw = Pt[w];
    const unsigned short* qB  = qb  + (size_t)bh * T_ * D_;
    const float*          kB  = kf  + (size_t)bh * T_ * D_;
    const unsigned short* kbB = kbp + (size_t)bh * T_ * D_;
    const unsigned short* vB  = vt  + (size_t)bh * D_ * T_;

    const int qr0 = qt * 64 + w * 16;
    const int qrow_g = qr0 + fr;                     // this lane's q-row

    // Q as B-frag: B[k][n]: n = lane&15 = q-row, k = qd*8+j
    bf16x8 aq0 = *(const bf16x8*)(qB + (size_t)(qr0 + fr) * D_ + qd * 8);
    bf16x8 aq1 = *(const bf16x8*)(qB + (size_t)(qr0 + fr) * D_ + 32 + qd * 8);

    // O^T accumulator: accT[ch][r] = O^T[d = ch*16 + qd*4 + r][q-row = fr]
    f32x4 accT[4] = {};
    float m_i = -1e30f, l_i = 0.0f;

    for (int jt = 0; jt <= qt; ++jt) {
        // K as A-frag: A[m][k]: m = k-col = lane&15 (rel), k = d = qd*8+j
        bf16x8 bk[8];
#pragma unroll
        for (int q8 = 0; q8 < 8; ++q8) {
            const size_t row = (size_t)(jt * 64 + (q8 >> 1) * 16 + fr);
            const int dof = (q8 & 1) * 32 + qd * 8;
            if (KB) bk[q8] = *(const bf16x8*)(kbB + row * D_ + dof);
            else {
                const float* p = kB + row * D_ + dof;
                bk[q8] = cvt8(*(const float4*)p, *(const float4*)(p + 4));
            }
        }

        // S^T = K Q^T : s4[nt][r] = S[q-row=fr][kcol = jt*64 + nt*16 + qd*4 + r]
        f32x4 s4[4] = {};
#pragma unroll
        for (int nt = 0; nt < 4; ++nt) {
            s4[nt] = __builtin_amdgcn_mfma_f32_16x16x32_bf16(bk[nt * 2 + 0], aq0, s4[nt], 0, 0, 0);
            s4[nt] = __builtin_amdgcn_mfma_f32_16x16x32_bf16(bk[nt * 2 + 1], aq1, s4[nt], 0, 0, 0);
        }

        // V^T as A-frag (issue early; consumed after softmax)
        bf16x8 bv[8];
#pragma unroll
        for (int q8 = 0; q8 < 8; ++q8)
            bv[q8] = *(const bf16x8*)(vB + (size_t)((q8 >> 1) * 16 + fr) * T_
                                      + jt * 64 + (q8 & 1) * 32 + qd * 8);

        // scale + causal mask (kcol <= qrow)
        const float sc = 0.125f;   // 1/sqrt(64)
        if (jt == qt) {
            const int kbase = jt * 64 + qd * 4;
#pragma unroll
            for (int nt = 0; nt < 4; ++nt)
#pragma unroll
            for (int r = 0; r < 4; ++r) {
                const int kcol = kbase + nt * 16 + r;
                s4[nt][r] = (kcol <= qrow_g) ? s4[nt][r] * sc : -1e30f;
            }
        } else {
#pragma unroll
            for (int nt = 0; nt < 4; ++nt)
#pragma unroll
            for (int r = 0; r < 4; ++r) s4[nt][r] *= sc;
        }

        // online softmax — in-lane over 16 regs, then xor16/xor32 across qd
        float mx = -1e30f;
#pragma unroll
        for (int nt = 0; nt < 4; ++nt) {
            float m2 = fmaxf(fmaxf(s4[nt][0], s4[nt][1]), fmaxf(s4[nt][2], s4[nt][3]));
            mx = fmaxf(mx, m2);
        }
        mx = fmaxf(mx, __shfl_xor(mx, 16));
        mx = fmaxf(mx, __shfl_xor(mx, 32));
        const float mnew = fmaxf(m_i, mx);
        const float alpha = __expf(m_i - mnew);
        m_i = mnew;

        float rs = 0.0f;
#pragma unroll
        for (int nt = 0; nt < 4; ++nt)
#pragma unroll
        for (int r = 0; r < 4; ++r) {
            const float pv = __expf(s4[nt][r] - mnew);
            s4[nt][r] = pv;
            rs += pv;
        }
        rs += __shfl_xor(rs, 16);
        rs += __shfl_xor(rs, 32);
        l_i = l_i * alpha + rs;

#pragma unroll
        for (int nt = 0; nt < 4; ++nt)
#pragma unroll
        for (int r = 0; r < 4; ++r) accT[nt][r] *= alpha;

        // P -> B-frag layout via wave-private LDS: Pw[q-row][kcol], b64 writes
#pragma unroll
        for (int nt = 0; nt < 4; ++nt) {
            union { unsigned short s[4]; unsigned long long u; } pk;
            pk.s[0] = f2bf(s4[nt][0]);
            pk.s[1] = f2bf(s4[nt][1]);
            pk.s[2] = f2bf(s4[nt][2]);
            pk.s[3] = f2bf(s4[nt][3]);
            *(unsigned long long*)&Pw[fr * 72 + nt * 16 + qd * 4] = pk.u;
        }
        const bf16x8 ap0 = *(const bf16x8*)&Pw[fr * 72 + qd * 8];
        const bf16x8 ap1 = *(const bf16x8*)&Pw[fr * 72 + 32 + qd * 8];

        // O^T += V^T P^T
#pragma unroll
        for (int nt = 0; nt < 4; ++nt) {
            accT[nt] = __builtin_amdgcn_mfma_f32_16x16x32_bf16(bv[nt * 2 + 0], ap0, accT[nt], 0, 0, 0);
            accT[nt] = __builtin_amdgcn_mfma_f32_16x16x32_bf16(bv[nt * 2 + 1], ap1, accT[nt], 0, 0, 0);
        }
    }

    // epilogue: O = O^T/l via per-wave LDS transpose, coalesced stores
    const float inv = 1.0f / l_i;
#pragma unroll
    for (int nt = 0; nt < 4; ++nt) {
        union { unsigned short s[4]; unsigned long long u; } ok;
        ok.s[0] = f2bf(accT[nt][0] * inv);
        ok.s[1] = f2bf(accT[nt][1] * inv);
        ok.s[2] = f2bf(accT[nt][2] * inv);
        ok.s[3] = f2bf(accT[nt][3] * inv);
        *(unsigned long long*)&Pw[fr * 72 + nt * 16 + qd * 4] = ok.u;
    }
    // lane l: row = l>>2 (q-row), d0 = (l&3)*16
    {
        const int row = lane >> 2, d0 = (lane & 3) * 16;
        const bf16x8 o0 = *(const bf16x8*)&Pw[row * 72 + d0];
        const bf16x8 o1 = *(const bf16x8*)&Pw[row * 72 + d0 + 8];
        unsigned short* op = attb + ((size_t)b * T_ + qr0 + row) * C_ + h * 64 + d0;
        *(bf16x8*)op = o0;
        *(bf16x8*)(op + 8) = o1;
    }
}

// ---------------------------------------------------------------------------
extern "C" void kernel_launch(void* const* d_in, const int* in_sizes, int n_in,
                              void* d_out, int out_size, void* d_ws, size_t ws_size,
                              hipStream_t stream)
{
    (void)in_sizes; (void)n_in; (void)out_size;
    const float* x  = (const float*)d_in[0];
    const float* Wq = (const float*)d_in[1];
    const float* Wk = (const float*)d_in[2];
    const float* Wv = (const float*)d_in[3];
    const float* Wo = (const float*)d_in[4];
    const float* bo = (const float*)d_in[5];

    float* out  = (float*)d_out;                       // (B,T,C)
    float* kout = out  + (size_t)M_ * C_;              // (B,H,T,D) fp32
    float* vout = kout + (size_t)B_ * H_ * T_ * D_;    // (B,H,T,D) fp32

    // ws: xb(8M) | wtb(8M) | qb(8M) | vbt(8M) | kb(8M, optional); attb aliases xb
    unsigned short* xb   = (unsigned short*)d_ws;
    unsigned short* wtb  = xb  + (size_t)M_ * C_;
    unsigned short* qb   = wtb + (size_t)4 * C_ * C_;
    unsigned short* vbt  = qb  + (size_t)M_ * C_;
    unsigned short* kb   = vbt + (size_t)M_ * C_;
    unsigned short* attb = xb;
    const bool use_kb = ws_size >= (size_t)40 * 1024 * 1024;

    cast_x<<<1024, 256, 0, stream>>>(x, xb, (M_ * C_) / 4);
    tcast_w<<<dim3(16, 16, 4), 256, 0, stream>>>(Wq, Wk, Wv, Wo, wtb);

    if (use_kb)
        gemm_qkv<1><<<dim3(24, M_ / 128), 256, 0, stream>>>(xb, wtb, qb, kout, vout, kb);
    else
        gemm_qkv<0><<<dim3(24, M_ / 128), 256, 0, stream>>>(xb, wtb, qb, kout, vout, kb);

    transpose_v<<<dim3(T_ / 64, B_ * H_), 256, 0, stream>>>(vout, vbt);

    if (use_kb)
        attn_mfma<true><<<1024, 256, 0, stream>>>(qb, kout, kb, vbt, attb);
    else
        attn_mfma<false><<<1024, 256, 0, stream>>>(qb, kout, kb, vbt, attb);

    gemm_o<<<dim3(8, M_ / 128), 256, 0, stream>>>(attb, wtb + (size_t)3 * C_ * C_, bo, out);
}